// Round 13
// baseline (54.811 us; speedup 1.0000x reference)
//
#include <hip/hip_runtime.h>

// B=8, N=2048, D=32, H=4, HD=8, BH=32
// ws layout (17.5MB):
//   q16    [32][2048][8]    f16 (1MB) @ 0     c1*log2e pre-folded
//   kf_ws  [32][128][64][4] f16 (2MB) @ 1MB   K in MFMA-A fragment order
//   vf_ws  [32][128][64][4] f16 (2MB) @ 3MB   V^T in MFMA-B frag order (+ones row d=8)
//   adj16  [64][128][64][8] f16 (8MB) @ 5MB   exp2(c2*adj), C-frag order, qt-pair packed
//   num_ws [2][8][2048][32] f32 (4MB) @ 13MB  attention numerators per jt-half
//   den_ws [2][32][2048]    f32 (.5MB)@ 17MB  softmax denominators per jt-half
//
// R13: 4bh x 4qt x 2 jt-half blocks -> 192MB L2 traffic (KV x32=128 + adj
// x8=64) at 512 blocks. Fixed-max softmax => jt-split halves write raw
// num/den; out_ln merges (n0+n1)/(d0+d1). XCD swizzle: 4-qtg adj slice
// (1MB) per XCD stays L2-resident.

typedef _Float16 f16;
typedef _Float16 f16x4 __attribute__((ext_vector_type(4)));
typedef _Float16 f16x8 __attribute__((ext_vector_type(8)));
typedef __fp16 h16x2 __attribute__((ext_vector_type(2)));
typedef __fp16 h16x8 __attribute__((ext_vector_type(8)));
typedef float f32x4 __attribute__((ext_vector_type(4)));

// Fused: blocks [0,2048) swizzle adj (+ constant-lane fill); [2048,3072) qkv.
__global__ __launch_bounds__(256) void prep_qkv_kernel(
    const float* __restrict__ x, const float* __restrict__ Wqkv,
    const float* __restrict__ bqkv, const float* __restrict__ adj,
    const float* __restrict__ gw_p, f16* __restrict__ q16,
    f16* __restrict__ kf_ws, f16* __restrict__ vf_ws,
    f16* __restrict__ adj16) {
  const float LOG2E = 1.4426950408889634f;
  float blend = 1.f / (1.f + __expf(-gw_p[0]));
  int tid = threadIdx.x;
  __shared__ float Ws[32 * 96];
  __shared__ float bsh[96];
  __shared__ float xs[16 * 32];

  if (blockIdx.x < 2048) {
    float c2 = blend * 5.f * LOG2E;
    int gid = blockIdx.x * 256 + tid;          // 8192 tiles * 64 lanes
    int tile = gid >> 6, lane = gid & 63;
    int qtp = tile >> 7, jt = tile & 127;
    int col = jt * 16 + (lane >> 4) * 4;
    f32x4 v0 = *(const f32x4*)(adj + (size_t)(qtp * 32 + (lane & 15)) * 2048 + col);
    f32x4 v1 = *(const f32x4*)(adj + (size_t)(qtp * 32 + 16 + (lane & 15)) * 2048 + col);
    f16x8 r;  // store exp2(c2*adj): consumed multiplicatively in attn
    r[0] = (f16)__builtin_amdgcn_exp2f(c2 * v0[0]);
    r[1] = (f16)__builtin_amdgcn_exp2f(c2 * v0[1]);
    r[2] = (f16)__builtin_amdgcn_exp2f(c2 * v0[2]);
    r[3] = (f16)__builtin_amdgcn_exp2f(c2 * v0[3]);
    r[4] = (f16)__builtin_amdgcn_exp2f(c2 * v1[0]);
    r[5] = (f16)__builtin_amdgcn_exp2f(c2 * v1[1]);
    r[6] = (f16)__builtin_amdgcn_exp2f(c2 * v1[2]);
    r[7] = (f16)__builtin_amdgcn_exp2f(c2 * v1[3]);
    *(f16x8*)(adj16 + (size_t)gid * 8) = r;
    if (gid < 262144) {  // 4096 k/v fragment tiles: constant lanes
      const f16x4 z = {};
      if (lane >= 32) *(f16x4*)(kf_ws + (size_t)gid * 4) = z;
      int dq = lane & 15;
      if (dq == 8) {
        f16x4 ones = {(f16)1.f, (f16)1.f, (f16)1.f, (f16)1.f};
        *(f16x4*)(vf_ws + (size_t)gid * 4) = ones;
      } else if (dq > 8) {
        *(f16x4*)(vf_ws + (size_t)gid * 4) = z;
      }
    }
  } else {
    float c1 = (1.f - blend) * 0.35355339059327373f * LOG2E;
    int blk = blockIdx.x - 2048;
    for (int i = tid; i < 32 * 96; i += 256) Ws[i] = Wqkv[i];
    if (tid < 96) bsh[tid] = bqkv[tid];
    int rowbase = blk * 16;
    for (int i = tid; i < 16 * 32; i += 256) xs[i] = x[rowbase * 32 + i];
    __syncthreads();
#pragma unroll
    for (int e = 0; e < 6; ++e) {
      int idx = tid + e * 256;
      int r = idx / 96, c = idx % 96;
      float acc = bsh[c];
#pragma unroll
      for (int k = 0; k < 32; ++k) acc += xs[r * 32 + k] * Ws[k * 96 + c];
      int nrow = rowbase + r;
      int b = nrow >> 11, n = nrow & 2047;
      int s = c >> 5, h = (c >> 3) & 3, d = c & 7;
      int bh = b * 4 + h;
      int jt = n >> 4, jr = n & 15;
      if (s == 0) {
        q16[((size_t)bh * 2048 + n) * 8 + d] = (f16)(acc * c1);
      } else if (s == 1) {
        int lane = ((d >> 2) << 4) | jr;   // K frag: lane=(d>>2)*16+jr, e=d&3
        kf_ws[(((size_t)bh * 128 + jt) * 64 + lane) * 4 + (d & 3)] = (f16)acc;
      } else {
        int lane = ((jr >> 2) << 4) | d;   // V frag: lane=(jr>>2)*16+d, e=jr&3
        vf_ws[(((size_t)bh * 128 + jt) * 64 + lane) * 4 + (jr & 3)] = (f16)acc;
      }
    }
  }
}

__global__ __launch_bounds__(512, 4) void attn_kernel(
    const f16* __restrict__ q16, const f16* __restrict__ kf_ws,
    const f16* __restrict__ vf_ws, const f16* __restrict__ adj16,
    float* __restrict__ num_ws, float* __restrict__ den_ws) {
  // XCD swizzle: chunk (=XCD) owns 4 qtg -> 1MB adj16 slice L2-resident.
  int blk = blockIdx.x;                 // 512 blocks
  int chunk = blk & 7;
  int within = blk >> 3;                // 0..63
  int qtg = chunk * 4 + (within >> 4);  // 32 qt-groups of 4
  int bhjt = within & 15;
  int bhg = bhjt & 7;                   // 8 batches (4 heads each)
  int jth = bhjt >> 3;                  // 2 jt-halves
  int tid = threadIdx.x;
  int w = tid >> 6, lane = tid & 63;
  int qth = w & 1, jq = w >> 1;         // 2 qt-halves x 4 j-quarters
  int lq = lane & 15, lh = lane >> 4;
  int bh0 = bhg * 4;
  int jt0 = jth * 64 + jq * 16;         // 16 jt per wave
  int qtp = qtg * 2 + qth;              // this wave's qt-pair (qt0=2*qtp even)
  int qt0 = qtp * 2;

  const f16* kp = kf_ws + (((size_t)bh0 * 128 + jt0) * 64 + lane) * 4;
  const f16* vp = vf_ws + (((size_t)bh0 * 128 + jt0) * 64 + lane) * 4;
  const f16* ap = adj16 + (((size_t)qtp * 128 + jt0) * 64 + lane) * 8;

  // Q fragments (c1 pre-folded): qf[u][m] for bh0+u, qt0+m
  f16x4 qf[4][2];
#pragma unroll
  for (int u = 0; u < 4; ++u)
#pragma unroll
    for (int m = 0; m < 2; ++m) {
      f16x4 t = {};
      if (lane < 32)
        t = *(const f16x4*)(q16 + ((size_t)(bh0 + u) * 2048 +
                                   (qt0 + m) * 16 + lq) * 8 + lh * 4);
      qf[u][m] = t;
    }

  f32x4 acc[4][2];
#pragma unroll
  for (int u = 0; u < 4; ++u)
#pragma unroll
    for (int m = 0; m < 2; ++m) acc[u][m] = (f32x4){0.f, 0.f, 0.f, 0.f};
  const f32x4 zero4 = {0.f, 0.f, 0.f, 0.f};

#pragma unroll 2
  for (int t = 0; t < 16; ++t) {
    f16x4 kf[4], vf[4];
#pragma unroll
    for (int u = 0; u < 4; ++u) {
      kf[u] = *(const f16x4*)(kp + u * 32768 + t * 256);   // 128*64*4 = 32768
      vf[u] = *(const f16x4*)(vp + u * 32768 + t * 256);
    }
    h16x8 av = *(const h16x8*)(ap + t * 512);
#pragma unroll
    for (int u = 0; u < 4; ++u) {
#pragma unroll
      for (int m = 0; m < 2; ++m) {
        f32x4 s = __builtin_amdgcn_mfma_f32_16x16x16f16(kf[u], qf[u][m], zero4, 0, 0, 0);
        int b4 = m * 4;
        float e0 = __builtin_amdgcn_exp2f(s[0]);
        float e1 = __builtin_amdgcn_exp2f(s[1]);
        float e2 = __builtin_amdgcn_exp2f(s[2]);
        float e3 = __builtin_amdgcn_exp2f(s[3]);
        h16x2 p01 = __builtin_amdgcn_cvt_pkrtz(e0, e1);
        h16x2 p23 = __builtin_amdgcn_cvt_pkrtz(e2, e3);
        h16x2 ea01 = {av[b4 + 0], av[b4 + 1]};
        h16x2 ea23 = {av[b4 + 2], av[b4 + 3]};
        p01 *= ea01;   // v_pk_mul_f16: p = exp2(s) * exp2(c2*adj)
        p23 *= ea23;
        f16x4 pa;
        pa[0] = (f16)(float)p01[0]; pa[1] = (f16)(float)p01[1];
        pa[2] = (f16)(float)p23[0]; pa[3] = (f16)(float)p23[1];
        acc[u][m] = __builtin_amdgcn_mfma_f32_16x16x16f16(pa, vf[u], acc[u][m], 0, 0, 0);
      }
    }
  }

  // merge 4 j-quarter partials per qt-half (48KB LDS): jq 1..3 dump, jq 0 adds.
  __shared__ f32x4 mlds[2][3][8][64];
  if (jq) {
#pragma unroll
    for (int u = 0; u < 4; ++u)
#pragma unroll
      for (int m = 0; m < 2; ++m) mlds[qth][jq - 1][u * 2 + m][lane] = acc[u][m];
  }
  __syncthreads();
  if (jq == 0) {
#pragma unroll
    for (int p = 0; p < 3; ++p)
#pragma unroll
      for (int u = 0; u < 4; ++u)
#pragma unroll
        for (int m = 0; m < 2; ++m) {
          f32x4 o = mlds[qth][p][u * 2 + m][lane];
          acc[u][m][0] += o[0]; acc[u][m][1] += o[1];
          acc[u][m][2] += o[2]; acc[u][m][3] += o[3];
        }
    // write raw numerators (lq<8) and denominators (lq==8); divide in out_ln.
    size_t joff = (size_t)jth << 19;    // 8*2048*32 floats per half
#pragma unroll
    for (int u = 0; u < 4; ++u) {
#pragma unroll
      for (int m = 0; m < 2; ++m) {
        f32x4 s = acc[u][m];
        int qt = qt0 + m;
        int n0 = qt * 16 + lh * 4;      // rows n0..n0+3 (reg r)
        if (lq < 8) {
          size_t base = joff + ((size_t)bhg * 2048 + n0) * 32 + u * 8 + lq;
          num_ws[base]      = s[0];
          num_ws[base + 32] = s[1];
          num_ws[base + 64] = s[2];
          num_ws[base + 96] = s[3];
        } else if (lq == 8) {
          size_t dbase = ((size_t)jth << 16) + ((size_t)(bh0 + u)) * 2048 + n0;
          den_ws[dbase]     = s[0];
          den_ws[dbase + 1] = s[1];
          den_ws[dbase + 2] = s[2];
          den_ws[dbase + 3] = s[3];
        }
      }
    }
  }
}

__global__ __launch_bounds__(256) void out_ln_kernel(
    const float* __restrict__ num_ws, const float* __restrict__ den_ws,
    const float* __restrict__ x, const float* __restrict__ Wout,
    const float* __restrict__ bout, const float* __restrict__ gamma,
    const float* __restrict__ beta, float* __restrict__ out) {
  __shared__ float Ws[32 * 32];
  __shared__ float bs[32], gs[32], bts[32];
  __shared__ float arow[8][32];
  int tid = threadIdx.x;
  for (int i = tid; i < 1024; i += 256) Ws[i] = Wout[i];
  if (tid < 32) { bs[tid] = bout[tid]; gs[tid] = gamma[tid]; bts[tid] = beta[tid]; }
  int row = blockIdx.x * 8 + (tid >> 5);   // row = b*2048 + n
  int d = tid & 31;
  int b = row >> 11, n = row & 2047;
  int h = d >> 3;
  float num = num_ws[(size_t)row * 32 + d] +
              num_ws[(1u << 19) + (size_t)row * 32 + d];
  float den = den_ws[((size_t)(b * 4 + h)) * 2048 + n] +
              den_ws[(1u << 16) + ((size_t)(b * 4 + h)) * 2048 + n];
  arow[tid >> 5][d] = num / den;
  __syncthreads();
  const float* ar = arow[tid >> 5];
  float acc = bs[d];
#pragma unroll
  for (int k = 0; k < 32; ++k) acc += ar[k] * Ws[k * 32 + d];
  float res = acc + x[(size_t)row * 32 + d];
  float s1 = res, s2 = res * res;
#pragma unroll
  for (int off = 16; off >= 1; off >>= 1) {
    s1 += __shfl_xor(s1, off);
    s2 += __shfl_xor(s2, off);
  }
  float mu = s1 * 0.03125f;
  float var = s2 * 0.03125f - mu * mu;
  float r = rsqrtf(var + 1e-5f);
  out[(size_t)row * 32 + d] = (res - mu) * r * gs[d] + bts[d];
}

extern "C" void kernel_launch(void* const* d_in, const int* in_sizes, int n_in,
                              void* d_out, int out_size, void* d_ws, size_t ws_size,
                              hipStream_t stream) {
  const float* x     = (const float*)d_in[0];
  const float* adj   = (const float*)d_in[1];
  const float* gw    = (const float*)d_in[2];
  const float* Wqkv  = (const float*)d_in[3];
  const float* bqkv  = (const float*)d_in[4];
  const float* Wout  = (const float*)d_in[5];
  const float* bout  = (const float*)d_in[6];
  const float* gamma = (const float*)d_in[7];
  const float* beta  = (const float*)d_in[8];
  float* out = (float*)d_out;

  char* wsb = (char*)d_ws;
  f16* q16       = (f16*)wsb;                     // 1MB
  f16* kf_ws     = (f16*)(wsb + (1 << 20));       // 2MB
  f16* vf_ws     = (f16*)(wsb + (3 << 20));       // 2MB
  f16* adj16     = (f16*)(wsb + (5 << 20));       // 8MB
  float* num_ws  = (float*)(wsb + (13 << 20));    // 4MB (2 halves)
  float* den_ws  = (float*)(wsb + (17 << 20));    // 512KB (2 halves)

  prep_qkv_kernel<<<3072, 256, 0, stream>>>(x, Wqkv, bqkv, adj, gw,
                                            q16, kf_ws, vf_ws, adj16);
  attn_kernel<<<512, 512, 0, stream>>>(q16, kf_ws, vf_ws, adj16, num_ws, den_ws);
  out_ln_kernel<<<2048, 256, 0, stream>>>(num_ws, den_ws, x, Wout, bout,
                                          gamma, beta, out);
}

// Round 14
// 46.222 us; speedup vs baseline: 1.1858x; 1.1858x over previous
//
#include <hip/hip_runtime.h>

// B=8, N=2048, D=32, H=4, HD=8, BH=32
// ws layout (15MB):
//   q16    [32][2048][8]   f16 (1MB) @ 0     c1*log2e pre-folded
//   kf_ws  [32][64][64][8] f16 (2MB) @ 1MB   K frags, jt-PAIR packed (e=0..3 -> even jt)
//   vf_ws  [32][64][64][8] f16 (2MB) @ 3MB   V^T frags, jt-pair packed (+ones d=8)
//   adj16  [64][128][64][8] f16 (8MB) @ 5MB  exp2(c2*adj), C-frag order, qt-pair packed
//   attn_ws[8][2048][32]   f32 (2MB) @ 13MB
//
// R14 = R12 (best, 47.1us) + (1) jt-pair-packed K/V: one dwordx4 = 2 j-tiles
// -> inner-loop load instrs halved (txn-issue was the limit per R13 analysis),
// (2) LDS-staged coalesced adj swizzle in prep.

typedef _Float16 f16;
typedef _Float16 f16x4 __attribute__((ext_vector_type(4)));
typedef _Float16 f16x8 __attribute__((ext_vector_type(8)));
typedef __fp16 h16x2 __attribute__((ext_vector_type(2)));
typedef __fp16 h16x8 __attribute__((ext_vector_type(8)));
typedef float f32x4 __attribute__((ext_vector_type(4)));

// Blocks [0,512): coalesced adj swizzle (64 qtp x 8 col-chunks) + const fill.
// Blocks [512,1536): qkv projection (16 rows each).
__global__ __launch_bounds__(256) void prep_qkv_kernel(
    const float* __restrict__ x, const float* __restrict__ Wqkv,
    const float* __restrict__ bqkv, const float* __restrict__ adj,
    const float* __restrict__ gw_p, f16* __restrict__ q16,
    f16* __restrict__ kf_ws, f16* __restrict__ vf_ws,
    f16* __restrict__ adj16) {
  const float LOG2E = 1.4426950408889634f;
  float blend = 1.f / (1.f + __expf(-gw_p[0]));
  int tid = threadIdx.x;
  __shared__ union {
    float als[32][260];                      // padded: stride 260 -> 2-way max
    struct { float Ws[32 * 96]; float bsh[96]; float xs[16 * 32]; } qk;
  } u;

  if (blockIdx.x < 512) {
    // ---- constant-lane fill for packed kf/vf (disjoint from qkv writes) ----
    int g = blockIdx.x * 256 + tid;          // 131072 = 32bh*64jtp*64lane
    int glane = g & 63;
    const f16x8 z8 = {};
    if (glane >= 32) *(f16x8*)(kf_ws + (size_t)g * 8) = z8;
    int glq = glane & 15;
    if (glq == 8) {
      f16x8 o8 = {(f16)1.f, (f16)1.f, (f16)1.f, (f16)1.f,
                  (f16)1.f, (f16)1.f, (f16)1.f, (f16)1.f};
      *(f16x8*)(vf_ws + (size_t)g * 8) = o8;
    } else if (glq > 8) {
      *(f16x8*)(vf_ws + (size_t)g * 8) = z8;
    }
    // ---- coalesced adj read -> LDS -> swizzled exp2 f16 write ----
    float c2 = blend * 5.f * LOG2E;
    int qtp = blockIdx.x >> 3;               // 0..63
    int chunk = blockIdx.x & 7;              // 256 cols each
    const float* src = adj + (size_t)(qtp * 32) * 2048 + chunk * 256;
#pragma unroll
    for (int i = 0; i < 8; ++i) {
      int idx = i * 1024 + tid * 4;          // 32 rows x 256 cols
      int row = idx >> 8, col = idx & 255;
      f32x4 v = *(const f32x4*)(src + (size_t)row * 2048 + col);
      *(f32x4*)&u.als[row][col] = v;
    }
    __syncthreads();
#pragma unroll
    for (int i = 0; i < 4; ++i) {
      int flat = i * 256 + tid;              // 16 jt x 64 lanes
      int jt_l = flat >> 6, lane = flat & 63;
      int lq = lane & 15, lh = lane >> 4;
      int col0 = jt_l * 16 + lh * 4;
      f16x8 r;
#pragma unroll
      for (int e = 0; e < 8; ++e)
        r[e] = (f16)__builtin_amdgcn_exp2f(
            c2 * u.als[(e < 4 ? 0 : 16) + lq][col0 + (e & 3)]);
      int jt = chunk * 16 + jt_l;
      *(f16x8*)(adj16 + (((size_t)qtp * 128 + jt) * 64 + lane) * 8) = r;
    }
  } else {
    float c1 = (1.f - blend) * 0.35355339059327373f * LOG2E;
    int blk = blockIdx.x - 512;
    for (int i = tid; i < 32 * 96; i += 256) u.qk.Ws[i] = Wqkv[i];
    if (tid < 96) u.qk.bsh[tid] = bqkv[tid];
    int rowbase = blk * 16;
    for (int i = tid; i < 16 * 32; i += 256) u.qk.xs[i] = x[rowbase * 32 + i];
    __syncthreads();
#pragma unroll
    for (int e = 0; e < 6; ++e) {
      int idx = tid + e * 256;
      int r = idx / 96, c = idx % 96;
      float acc = u.qk.bsh[c];
#pragma unroll
      for (int k = 0; k < 32; ++k) acc += u.qk.xs[r * 32 + k] * u.qk.Ws[k * 96 + c];
      int nrow = rowbase + r;
      int b = nrow >> 11, n = nrow & 2047;
      int s = c >> 5, h = (c >> 3) & 3, d = c & 7;
      int bh = b * 4 + h;
      int jt = n >> 4, jr = n & 15;
      if (s == 0) {
        q16[((size_t)bh * 2048 + n) * 8 + d] = (f16)(acc * c1);
      } else if (s == 1) {
        int lane = ((d >> 2) << 4) | jr;     // K frag lane
        kf_ws[(((size_t)bh * 64 + (jt >> 1)) * 64 + lane) * 8 +
              (jt & 1) * 4 + (d & 3)] = (f16)acc;
      } else {
        int lane = ((jr >> 2) << 4) | d;     // V frag lane
        vf_ws[(((size_t)bh * 64 + (jt >> 1)) * 64 + lane) * 8 +
              (jt & 1) * 4 + (jr & 3)] = (f16)acc;
      }
    }
  }
}

__global__ __launch_bounds__(512, 4) void attn_kernel(
    const f16* __restrict__ q16, const f16* __restrict__ kf_ws,
    const f16* __restrict__ vf_ws, const f16* __restrict__ adj16,
    float* __restrict__ attn_ws) {
  // XCD swizzle (as R12): each chunk owns 4 qtq -> 1MB adj16 slice in L2.
  int blk = blockIdx.x;                 // 512 blocks
  int chunk = blk & 7;
  int within = blk >> 3;                // 0..63
  int bhp = within & 15;                // 16 bh-pairs (adj-sharing, same XCD)
  int qtq = (chunk << 2) | (within >> 4);  // 32 qt-quads
  int tid = threadIdx.x;
  int w = tid >> 6, lane = tid & 63;    // w = j-split (16 jt = 8 jt-pairs)
  int lq = lane & 15, lh = lane >> 4;
  int bh0 = bhp * 2;

  // packed K/V streams: jtp0 = w*8; per-jtp stride 512 f16; bh stride 32768
  const f16* kp = kf_ws + (((size_t)bh0 * 64 + w * 8) * 64 + lane) * 8;
  const f16* vp = vf_ws + (((size_t)bh0 * 64 + w * 8) * 64 + lane) * 8;
  const f16* ap0 = adj16 + (((size_t)(qtq * 2) * 128 + w * 16) * 64 + lane) * 8;
  const f16* ap1 = ap0 + (size_t)128 * 64 * 8;

  // Q fragments (c1 pre-folded in q16): qf[u][m] for bh=bh0+u, qt=qtq*4+m
  f16x4 qf[2][4];
#pragma unroll
  for (int uu = 0; uu < 2; ++uu)
#pragma unroll
    for (int m = 0; m < 4; ++m) {
      f16x4 t = {};
      if (lane < 32)
        t = *(const f16x4*)(q16 + ((size_t)(bh0 + uu) * 2048 +
                                   (qtq * 4 + m) * 16 + lq) * 8 + lh * 4);
      qf[uu][m] = t;
    }

  f32x4 acc[2][4];
#pragma unroll
  for (int uu = 0; uu < 2; ++uu)
#pragma unroll
    for (int m = 0; m < 4; ++m) acc[uu][m] = (f32x4){0.f, 0.f, 0.f, 0.f};
  const f32x4 zero4 = {0.f, 0.f, 0.f, 0.f};

#pragma unroll 2
  for (int tp = 0; tp < 8; ++tp) {      // 8 jt-pairs = 16 j-tiles
    f16x8 kf80 = *(const f16x8*)(kp + tp * 512);
    f16x8 kf81 = *(const f16x8*)(kp + 32768 + tp * 512);
    f16x8 vf80 = *(const f16x8*)(vp + tp * 512);
    f16x8 vf81 = *(const f16x8*)(vp + 32768 + tp * 512);
    h16x8 a0a = *(const h16x8*)(ap0 + (tp * 2) * 512);
    h16x8 a0b = *(const h16x8*)(ap0 + (tp * 2 + 1) * 512);
    h16x8 a1a = *(const h16x8*)(ap1 + (tp * 2) * 512);
    h16x8 a1b = *(const h16x8*)(ap1 + (tp * 2 + 1) * 512);
#pragma unroll
    for (int jh = 0; jh < 2; ++jh) {    // the two j-tiles in the pair
      f16x4 kf0 = {kf80[jh * 4], kf80[jh * 4 + 1], kf80[jh * 4 + 2], kf80[jh * 4 + 3]};
      f16x4 kf1 = {kf81[jh * 4], kf81[jh * 4 + 1], kf81[jh * 4 + 2], kf81[jh * 4 + 3]};
      f16x4 vf0 = {vf80[jh * 4], vf80[jh * 4 + 1], vf80[jh * 4 + 2], vf80[jh * 4 + 3]};
      f16x4 vf1 = {vf81[jh * 4], vf81[jh * 4 + 1], vf81[jh * 4 + 2], vf81[jh * 4 + 3]};
      h16x8 av0 = jh ? a0b : a0a;
      h16x8 av1 = jh ? a1b : a1a;
#pragma unroll
      for (int uu = 0; uu < 2; ++uu) {
        f16x4 kfu = uu ? kf1 : kf0;
        f16x4 vfu = uu ? vf1 : vf0;
#pragma unroll
        for (int m = 0; m < 4; ++m) {
          f32x4 s = __builtin_amdgcn_mfma_f32_16x16x16f16(kfu, qf[uu][m], zero4, 0, 0, 0);
          h16x8 av = (m < 2) ? av0 : av1;
          int b4 = (m & 1) * 4;
          float e0 = __builtin_amdgcn_exp2f(s[0]);
          float e1 = __builtin_amdgcn_exp2f(s[1]);
          float e2 = __builtin_amdgcn_exp2f(s[2]);
          float e3 = __builtin_amdgcn_exp2f(s[3]);
          h16x2 p01 = __builtin_amdgcn_cvt_pkrtz(e0, e1);
          h16x2 p23 = __builtin_amdgcn_cvt_pkrtz(e2, e3);
          h16x2 ea01 = {av[b4 + 0], av[b4 + 1]};
          h16x2 ea23 = {av[b4 + 2], av[b4 + 3]};
          p01 *= ea01;   // v_pk_mul_f16: p = exp2(s) * exp2(c2*adj)
          p23 *= ea23;
          f16x4 pa;
          pa[0] = (f16)(float)p01[0]; pa[1] = (f16)(float)p01[1];
          pa[2] = (f16)(float)p23[0]; pa[3] = (f16)(float)p23[1];
          acc[uu][m] = __builtin_amdgcn_mfma_f32_16x16x16f16(pa, vfu, acc[uu][m], 0, 0, 0);
        }
      }
    }
  }

  // merge 8 j-split partials; parallel epilogue: wave w reduces slot p=w.
  __shared__ f32x4 mlds[8][8][64];  // 64KB
#pragma unroll
  for (int uu = 0; uu < 2; ++uu)
#pragma unroll
    for (int m = 0; m < 4; ++m) mlds[w][uu * 4 + m][lane] = acc[uu][m];
  __syncthreads();
  int p = w;
  f32x4 sum = mlds[0][p][lane];
#pragma unroll
  for (int s = 1; s < 8; ++s) {
    f32x4 o = mlds[s][p][lane];
    sum[0] += o[0]; sum[1] += o[1]; sum[2] += o[2]; sum[3] += o[3];
  }
  // sum(l,r) = out[q = qt*16 + lh*4 + r][d = lq]; denominator at d=8
  int dsrc = (lane & 48) | 8;
  float d0 = __shfl(sum[0], dsrc);
  float d1 = __shfl(sum[1], dsrc);
  float d2 = __shfl(sum[2], dsrc);
  float d3 = __shfl(sum[3], dsrc);
  if (lq < 8) {
    int bh = bh0 + (p >> 2);
    int b = bh >> 2, h = bh & 3;
    int qt0 = (qtq * 4 + (p & 3)) * 16;
    size_t base = ((size_t)b * 2048 + qt0 + lh * 4) * 32 + h * 8 + lq;
    attn_ws[base]      = sum[0] / d0;
    attn_ws[base + 32] = sum[1] / d1;
    attn_ws[base + 64] = sum[2] / d2;
    attn_ws[base + 96] = sum[3] / d3;
  }
}

__global__ __launch_bounds__(256) void out_ln_kernel(
    const float* __restrict__ attn_ws, const float* __restrict__ x,
    const float* __restrict__ Wout, const float* __restrict__ bout,
    const float* __restrict__ gamma, const float* __restrict__ beta,
    float* __restrict__ out) {
  __shared__ float Ws[32 * 32];
  __shared__ float bs[32], gs[32], bts[32];
  int tid = threadIdx.x;
  for (int i = tid; i < 1024; i += 256) Ws[i] = Wout[i];
  if (tid < 32) { bs[tid] = bout[tid]; gs[tid] = gamma[tid]; bts[tid] = beta[tid]; }
  __syncthreads();
  int row = blockIdx.x * 8 + (tid >> 5);
  int d = tid & 31;
  const float* ar = attn_ws + (size_t)row * 32;
  float acc = bs[d];
#pragma unroll
  for (int k = 0; k < 32; ++k) acc += ar[k] * Ws[k * 32 + d];
  float res = acc + x[(size_t)row * 32 + d];
  float s1 = res, s2 = res * res;
#pragma unroll
  for (int off = 16; off >= 1; off >>= 1) {
    s1 += __shfl_xor(s1, off);
    s2 += __shfl_xor(s2, off);
  }
  float mu = s1 * 0.03125f;
  float var = s2 * 0.03125f - mu * mu;
  float r = rsqrtf(var + 1e-5f);
  out[(size_t)row * 32 + d] = (res - mu) * r * gs[d] + bts[d];
}

extern "C" void kernel_launch(void* const* d_in, const int* in_sizes, int n_in,
                              void* d_out, int out_size, void* d_ws, size_t ws_size,
                              hipStream_t stream) {
  const float* x     = (const float*)d_in[0];
  const float* adj   = (const float*)d_in[1];
  const float* gw    = (const float*)d_in[2];
  const float* Wqkv  = (const float*)d_in[3];
  const float* bqkv  = (const float*)d_in[4];
  const float* Wout  = (const float*)d_in[5];
  const float* bout  = (const float*)d_in[6];
  const float* gamma = (const float*)d_in[7];
  const float* beta  = (const float*)d_in[8];
  float* out = (float*)d_out;

  char* wsb = (char*)d_ws;
  f16* q16       = (f16*)wsb;                     // 1MB
  f16* kf_ws     = (f16*)(wsb + (1 << 20));       // 2MB
  f16* vf_ws     = (f16*)(wsb + (3 << 20));       // 2MB
  f16* adj16     = (f16*)(wsb + (5 << 20));       // 8MB
  float* attn_ws = (float*)(wsb + (13 << 20));    // 2MB

  prep_qkv_kernel<<<1536, 256, 0, stream>>>(x, Wqkv, bqkv, adj, gw,
                                            q16, kf_ws, vf_ws, adj16);
  attn_kernel<<<512, 512, 0, stream>>>(q16, kf_ws, vf_ws, adj16, attn_ws);
  out_ln_kernel<<<2048, 256, 0, stream>>>(attn_ws, x, Wout, bout, gamma, beta, out);
}